// Round 3
// baseline (214.853 us; speedup 1.0000x reference)
//
#include <hip/hip_runtime.h>
#include <math.h>

#define PP   7
#define NDIR 49
#define CIN  3
#define KK   147      // CIN * 49
#define KPAD 160      // bf16 weight row stride: 5 k-steps of 32, zero-padded tail
#define EE   384
#define HH   224
#define WW   224
#define GG   16       // patches per block
#define TB   256
#define SSTR 17       // samp LDS row stride (+1 pad: conflict-free GEMM reads)
#define NPX  112      // GG*PP pixel columns per block strip

typedef __attribute__((ext_vector_type(8))) __bf16 bf16x8;
typedef __attribute__((ext_vector_type(4))) float  f32x4;

__device__ __forceinline__ float sigmoidf_(float v) {
    return 1.0f / (1.0f + expf(-v));
}

// ---- K0: pack proj_w (E,K) fp32 -> bf16 [E][KPAD], zero-padded (RNE like (__bf16) cast)
__global__ void pack_pw_kernel(const float* __restrict__ pw, unsigned short* __restrict__ pwB) {
    int idx = blockIdx.x * blockDim.x + threadIdx.x;
    if (idx < EE * KPAD) {
        int e = idx / KPAD;
        int k = idx - e * KPAD;
        float v = (k < KK) ? pw[e * KK + k] : 0.0f;
        __bf16 h = (__bf16)v;
        pwB[idx] = *(unsigned short*)&h;
    }
}

// ---- K1: fused metric-conv + derived params + gather + MFMA projection GEMM.
// One block = 16 patches (one 7x112 pixel strip), planar-x gather (no repack:
// round-2 lesson — pack_x costs ~18 us of BW to save ~10 us here; net loss).
// __launch_bounds__(256,6): VGPR cap ~84. Round-1 lesson: unbounded -> 100 VGPR,
// occupancy collapse. Round-2 lesson: (256,8) -> 24 VGPR, zero ILP, latency-bound
// at 31% VALUBusy. 6 blocks x 4 waves = 24 waves/CU = measured occupancy anyway.
__launch_bounds__(TB, 6)
__global__ void fused_kernel(const float* __restrict__ x,
                             const float* __restrict__ mw,
                             const float* __restrict__ mb,
                             const unsigned short* __restrict__ pwB,
                             const float* __restrict__ pb,
                             float* __restrict__ out) {
    __shared__ float mws[7 * KK];        // 4116 B
    __shared__ float dirs[NDIR][3];      //  588 B
    __shared__ float par_s[GG][8];       //  512 B
    __shared__ float der_s[GG][5];       //  320 B
    // union buffer: phase A = staged strip [3][7][112] = 2352 fl;
    // phase B = samp[147][17] = 2499 fl.  Total LDS ~16 KB.
    __shared__ __align__(16) float buf[2512];

    const int t   = threadIdx.x;
    const int blk = blockIdx.x;
    const int b   = blk >> 6;
    const int rem = blk & 63;
    const int hp  = rem >> 1;
    const int wp0 = (rem & 1) * GG;
    const size_t m0 = (size_t)blk * GG;
    const int row0 = hp * PP;
    const int col0 = wp0 * PP;

    const float* xb = x + (size_t)b * (CIN * HH * WW);

    // ---- init: metric weights + direction table
    for (int i = t; i < 7 * KK; i += TB) mws[i] = mw[i];
    if (t >= 64 && t < 64 + NDIR) {
        int n = t - 64;
        float u0, u1, s;
        if (n == 0)      { u0 = 1.0f; u1 = 0.0f; s = 0.0f; }
        else if (n < 9)  { float th = (float)(n - 1)  * 0.78539816339744831f; u0 = cosf(th); u1 = sinf(th); s = 0.33333334f; }
        else if (n < 25) { float th = (float)(n - 9)  * 0.39269908169872414f; u0 = cosf(th); u1 = sinf(th); s = 0.66666669f; }
        else             { float th = (float)(n - 25) * 0.26179938779914941f; u0 = cosf(th); u1 = sinf(th); s = 1.0f; }
        dirs[n][0] = u0; dirs[n][1] = u1; dirs[n][2] = s;
    }

    // ---- stage the block's 3x7x112 pixel strip into LDS (coalesced scalar)
    for (int item = t; item < CIN * 7 * NPX; item += TB) {
        int c = item / (7 * NPX), r2 = item - c * (7 * NPX);
        int i = r2 / NPX, px = r2 - i * NPX;
        buf[item] = xb[(size_t)c * (HH * WW) + (size_t)(row0 + i) * WW + col0 + px];
    }
    __syncthreads();

    // ---- metric conv: 7 params x 16 patches = 112 dot products of length 147.
    // 3 independent accumulator chains (per channel): serial FMA latency
    // 147*4cy -> ~49*4cy between barriers.
    if (t < 112) {
        int prm = t >> 4, g = t & 15;
        const float* wrow = &mws[prm * KK];
        float acc0 = 0.0f, acc1 = 0.0f, acc2 = 0.0f;
        #pragma unroll 1
        for (int i = 0; i < 7; ++i) {
            const float* b0 = &buf[(0 * 7 + i) * NPX + g * 7];
            const float* b1 = &buf[(1 * 7 + i) * NPX + g * 7];
            const float* b2 = &buf[(2 * 7 + i) * NPX + g * 7];
            const float* w0 = &wrow[i * 7];
            const float* w1 = &wrow[49 + i * 7];
            const float* w2 = &wrow[98 + i * 7];
            #pragma unroll
            for (int j = 0; j < 7; ++j) {
                acc0 = fmaf(b0[j], w0[j], acc0);
                acc1 = fmaf(b1[j], w1[j], acc1);
                acc2 = fmaf(b2[j], w2[j], acc2);
            }
        }
        par_s[g][prm] = mb[prm] + acc0 + acc1 + acc2;
    }
    __syncthreads();

    // ---- derived quantities (proven math)
    if (t < GG) {
        float a0 = par_s[t][0], a1 = par_s[t][1], a2 = par_s[t][2], a3 = par_s[t][3];
        float a4 = par_s[t][4], a5 = par_s[t][5], a6 = par_s[t][6];
        float nrm = sqrtf(a0 * a0 + a1 * a1);
        float inv = 1.0f / fmaxf(nrm, 1e-12f);
        float v0 = a0 * inv, v1 = a1 * inv;
        float e0 = 2.0f * sigmoidf_(a2);
        float e1 = 2.0f * sigmoidf_(a3);
        float sc = 0.5f + 1.5f * sigmoidf_(a4);
        e0 *= sc; e1 *= sc;
        float wn  = sqrtf(a5 * a5 + a6 * a6);
        float wsc = 0.5f * sigmoidf_(wn);
        der_s[t][0] = e0 * v0 * v0 + e1 * v1 * v1;
        der_s[t][1] = (e0 - e1) * v0 * v1;
        der_s[t][2] = e0 * v1 * v1 + e1 * v0 * v0;
        der_s[t][3] = a5 * wsc;
        der_s[t][4] = a6 * wsc;
    }
    __syncthreads();

    // ---- positions + bilinear gather into samp (buf reused: strip is dead).
    // 4 explicitly-unrolled predicated rounds: independent rounds' loads overlap.
    // Branchless: clamped in-bounds loads, validity folded into the weights.
    #pragma unroll
    for (int rep = 0; rep < 4; ++rep) {
        int item = rep * TB + t;
        if (item < GG * NDIR) {
            int g = item / NDIR;
            int n = item - g * NDIR;
            float u0 = dirs[n][0], u1 = dirs[n][1], s = dirs[n][2];
            float M00 = der_s[g][0], M01 = der_s[g][1], M11 = der_s[g][2];
            float w0 = der_s[g][3], w1 = der_s[g][4];
            float quad  = u0 * u0 * M00 + 2.0f * u0 * u1 * M01 + u1 * u1 * M11;
            float drift = w0 * u0 + w1 * u1;
            float F = sqrtf(quad + 1e-6f) + drift;
            float r = s / (F + 1e-6f);
            float py = (float)(row0 + 3) + u1 * r;
            float px = (float)(col0 + g * PP + 3) + u0 * r;
            float y0f = floorf(py), x0f = floorf(px);
            float y1f = y0f + 1.0f, x1f = x0f + 1.0f;
            float wy = py - y0f, wx = px - x0f;
            float c00 = (1.0f - wy) * (1.0f - wx);
            float c01 = (1.0f - wy) * wx;
            float c10 = wy * (1.0f - wx);
            float c11 = wy * wx;
            bool vy0 = (y0f >= 0.0f) && (y0f <= (float)(HH - 1));
            bool vy1 = (y1f >= 0.0f) && (y1f <= (float)(HH - 1));
            bool vx0 = (x0f >= 0.0f) && (x0f <= (float)(WW - 1));
            bool vx1 = (x1f >= 0.0f) && (x1f <= (float)(WW - 1));
            c00 *= (vy0 && vx0) ? 1.0f : 0.0f;
            c01 *= (vy0 && vx1) ? 1.0f : 0.0f;
            c10 *= (vy1 && vx0) ? 1.0f : 0.0f;
            c11 *= (vy1 && vx1) ? 1.0f : 0.0f;
            int iy0 = (int)fminf(fmaxf(y0f, 0.0f), (float)(HH - 1));
            int iy1 = (int)fminf(fmaxf(y1f, 0.0f), (float)(HH - 1));
            int ix0 = (int)fminf(fmaxf(x0f, 0.0f), (float)(WW - 1));
            int ix1 = (int)fminf(fmaxf(x1f, 0.0f), (float)(WW - 1));
            int o00 = iy0 * WW + ix0, o01 = iy0 * WW + ix1;
            int o10 = iy1 * WW + ix0, o11 = iy1 * WW + ix1;
            #pragma unroll
            for (int c = 0; c < CIN; ++c) {
                const float* xc = xb + c * (HH * WW);
                float v00 = xc[o00], v01 = xc[o01], v10 = xc[o10], v11 = xc[o11];
                buf[(c * NDIR + n) * SSTR + g] =
                    v00 * c00 + v01 * c01 + v10 * c10 + v11 * c11;
            }
        }
    }
    __syncthreads();

    // ---- MFMA projection GEMM, operand-SWAPPED: A = pw rows (M=e), B = samp
    // (N=m). A/B lane layouts are symmetric (idx=lane&15, k=(lane>>4)*8+j), so
    // registers are unchanged vs the old order; D layout (col=lane&15=m,
    // row=(lane>>4)*4+reg=e_local) makes each lane own 4 CONSECUTIVE e for one
    // output row -> global_store_dwordx4 (6 stores/thread instead of 24 scalar).
    const int lane = t & 63;
    const int wv   = t >> 6;           // 0..3; wave handles 6 E-tiles
    const int nrow = lane & 15;        // m within block / A-row selector
    const int hi   = lane >> 4;        // k-chunk selector / e-subrow

    bf16x8 sfr[5];
    #pragma unroll
    for (int ks = 0; ks < 5; ++ks) {
        #pragma unroll
        for (int j = 0; j < 8; ++j) {
            int k = ks * 32 + hi * 8 + j;
            float v = (k < KK) ? buf[k * SSTR + nrow] : 0.0f;
            sfr[ks][j] = (__bf16)v;
        }
    }

    float* orow = out + (m0 + nrow) * EE;
    #pragma unroll
    for (int q = 0; q < 6; ++q) {
        int tile = wv * 6 + q;
        int erow = tile * 16 + nrow;
        const unsigned short* arow = pwB + (size_t)erow * KPAD + hi * 8;
        f32x4 acc = {0.0f, 0.0f, 0.0f, 0.0f};
        #pragma unroll
        for (int ks = 0; ks < 5; ++ks) {
            bf16x8 afr = *(const bf16x8*)&arow[ks * 32];
            acc = __builtin_amdgcn_mfma_f32_16x16x32_bf16(afr, sfr[ks], acc, 0, 0, 0);
        }
        int e0 = tile * 16 + hi * 4;
        f32x4 b4 = *(const f32x4*)&pb[e0];
        f32x4 o = acc + b4;
        *(f32x4*)&orow[e0] = o;
    }
}

extern "C" void kernel_launch(void* const* d_in, const int* in_sizes, int n_in,
                              void* d_out, int out_size, void* d_ws, size_t ws_size,
                              hipStream_t stream) {
    const float* x  = (const float*)d_in[0];
    const float* mw = (const float*)d_in[1];
    const float* mb = (const float*)d_in[2];
    const float* pw = (const float*)d_in[3];
    const float* pb = (const float*)d_in[4];
    float* out = (float*)d_out;

    unsigned short* pwB = (unsigned short*)d_ws;   // 120 KB

    const int B = in_sizes[0] / (CIN * HH * WW);   // 64

    pack_pw_kernel<<<(EE * KPAD + 255) / 256, 256, 0, stream>>>(pw, pwB);
    fused_kernel<<<B * 64, TB, 0, stream>>>(x, mw, mb, pwB, pb, out);
}

// Round 4
// 206.127 us; speedup vs baseline: 1.0423x; 1.0423x over previous
//
#include <hip/hip_runtime.h>
#include <math.h>

#define PP   7
#define NDIR 49
#define CIN  3
#define KK   147      // CIN * 49
#define KPAD 160      // bf16 weight row stride: 5 k-steps of 32, zero-padded tail
#define EE   384
#define HH   224
#define WW   224
#define GG   16       // patches per block
#define TB   256
#define SSTR 17       // samp LDS row stride (+1 pad: conflict-free GEMM reads)
#define NPX  112      // GG*PP pixel columns per block strip

typedef __attribute__((ext_vector_type(8))) __bf16 bf16x8;
typedef __attribute__((ext_vector_type(4))) float  f32x4;

__device__ __forceinline__ float sigmoidf_(float v) {
    return 1.0f / (1.0f + expf(-v));
}

// ---- K0: fused pack. (a) proj_w (E,K) fp32 -> bf16 [E][KPAD]; (b) x NCHW -> NHW4
// fp32 (channel-interleaved float4, 4th lane zero). Round-3 lesson: the packed
// image is worth ~43 us inside the fused gather (4x dwordx4 vs 12x scattered
// dword per sample) for ~16 us of streaming cost here. Net big win.
__global__ void pack_kernel(const float* __restrict__ x,
                            const float* __restrict__ pw,
                            float* __restrict__ xp,
                            unsigned short* __restrict__ pwB,
                            int npix4) {
    int idx = blockIdx.x * blockDim.x + threadIdx.x;
    if (idx < EE * KPAD) {
        int e = idx / KPAD;
        int k = idx - e * KPAD;
        float v = (k < KK) ? pw[e * KK + k] : 0.0f;
        __bf16 h = (__bf16)v;
        pwB[idx] = *(unsigned short*)&h;
    }
    if (idx < npix4) {
        const int ppi = HH * WW / 4;         // 12544 pixel-quads per image
        int b = idx / ppi;
        int p = (idx - b * ppi) * 4;
        const float* xb = x + (size_t)b * (CIN * HH * WW) + p;
        f32x4 r0 = *(const f32x4*)(xb);
        f32x4 r1 = *(const f32x4*)(xb + HH * WW);
        f32x4 r2 = *(const f32x4*)(xb + 2 * HH * WW);
        float* op = xp + ((size_t)b * (HH * WW) + p) * 4;
        #pragma unroll
        for (int i = 0; i < 4; ++i) {
            f32x4 v = {r0[i], r1[i], r2[i], 0.0f};
            *(f32x4*)(op + i * 4) = v;
        }
    }
}

// per-item gather geometry: sample position -> 4 corner offsets + 4 masked coefs
__device__ __forceinline__ void geom_(int item, int row0, int col0,
                                      const float dirs[NDIR][3], const float der[GG][5],
                                      int& g, int& n,
                                      int& o00, int& o01, int& o10, int& o11,
                                      float& c00, float& c01, float& c10, float& c11) {
    g = item / NDIR;
    n = item - g * NDIR;
    float u0 = dirs[n][0], u1 = dirs[n][1], s = dirs[n][2];
    float M00 = der[g][0], M01 = der[g][1], M11 = der[g][2];
    float w0 = der[g][3], w1 = der[g][4];
    float quad  = u0 * u0 * M00 + 2.0f * u0 * u1 * M01 + u1 * u1 * M11;
    float drift = w0 * u0 + w1 * u1;
    float F = sqrtf(quad + 1e-6f) + drift;
    float r = s / (F + 1e-6f);
    float py = (float)(row0 + 3) + u1 * r;
    float px = (float)(col0 + g * PP + 3) + u0 * r;
    float y0f = floorf(py), x0f = floorf(px);
    float y1f = y0f + 1.0f, x1f = x0f + 1.0f;
    float wy = py - y0f, wx = px - x0f;
    c00 = (1.0f - wy) * (1.0f - wx);
    c01 = (1.0f - wy) * wx;
    c10 = wy * (1.0f - wx);
    c11 = wy * wx;
    bool vy0 = (y0f >= 0.0f) && (y0f <= (float)(HH - 1));
    bool vy1 = (y1f >= 0.0f) && (y1f <= (float)(HH - 1));
    bool vx0 = (x0f >= 0.0f) && (x0f <= (float)(WW - 1));
    bool vx1 = (x1f >= 0.0f) && (x1f <= (float)(WW - 1));
    c00 *= (vy0 && vx0) ? 1.0f : 0.0f;
    c01 *= (vy0 && vx1) ? 1.0f : 0.0f;
    c10 *= (vy1 && vx0) ? 1.0f : 0.0f;
    c11 *= (vy1 && vx1) ? 1.0f : 0.0f;
    int iy0 = (int)fminf(fmaxf(y0f, 0.0f), (float)(HH - 1));
    int iy1 = (int)fminf(fmaxf(y1f, 0.0f), (float)(HH - 1));
    int ix0 = (int)fminf(fmaxf(x0f, 0.0f), (float)(WW - 1));
    int ix1 = (int)fminf(fmaxf(x1f, 0.0f), (float)(WW - 1));
    o00 = iy0 * WW + ix0; o01 = iy0 * WW + ix1;
    o10 = iy1 * WW + ix0; o11 = iy1 * WW + ix1;
}

// ---- K1: fused metric-conv + derived params + packed gather + MFMA GEMM.
// (256,6): VGPR cap ~84 — enough to keep 8 gather loads in flight (the point),
// low enough for 24 waves/CU (measured occupancy plateau anyway).
__launch_bounds__(TB, 6)
__global__ void fused_kernel(const float* __restrict__ x,    // planar (fallback)
                             const float* __restrict__ xp,   // packed NHW4 (main)
                             const float* __restrict__ mw,
                             const float* __restrict__ mb,
                             const unsigned short* __restrict__ pwB,
                             const float* __restrict__ pb,
                             float* __restrict__ out) {
    __shared__ float mws[7 * KK];        // 4116 B
    __shared__ float dirs[NDIR][3];      //  588 B
    __shared__ float par_s[GG][8];       //  512 B
    __shared__ float der_s[GG][5];       //  320 B
    // union buffer: phase A = staged strip [7][112][4] = 3136 fl;
    // phase B = samp[147][17] = 2499 fl.  Total LDS ~18 KB -> 8 blocks max.
    __shared__ __align__(16) float buf[3136];

    const int t   = threadIdx.x;
    const int blk = blockIdx.x;
    const int b   = blk >> 6;
    const int rem = blk & 63;
    const int hp  = rem >> 1;
    const int wp0 = (rem & 1) * GG;
    const size_t m0 = (size_t)blk * GG;
    const int row0 = hp * PP;
    const int col0 = wp0 * PP;

    // ---- init: metric weights + direction table
    for (int i = t; i < 7 * KK; i += TB) mws[i] = mw[i];
    if (t >= 64 && t < 64 + NDIR) {
        int n = t - 64;
        float u0, u1, s;
        if (n == 0)      { u0 = 1.0f; u1 = 0.0f; s = 0.0f; }
        else if (n < 9)  { float th = (float)(n - 1)  * 0.78539816339744831f; u0 = cosf(th); u1 = sinf(th); s = 0.33333334f; }
        else if (n < 25) { float th = (float)(n - 9)  * 0.39269908169872414f; u0 = cosf(th); u1 = sinf(th); s = 0.66666669f; }
        else             { float th = (float)(n - 25) * 0.26179938779914941f; u0 = cosf(th); u1 = sinf(th); s = 1.0f; }
        dirs[n][0] = u0; dirs[n][1] = u1; dirs[n][2] = s;
    }

    // ---- stage the block's 7x112 strip into LDS (coalesced dwordx4)
    const size_t pbase = (size_t)b * (HH * WW);
    for (int item = t; item < 7 * NPX; item += TB) {
        int i = item / NPX, px = item - i * NPX;
        f32x4 v = *(const f32x4*)(xp + (pbase + (size_t)(row0 + i) * WW + col0 + px) * 4);
        *(f32x4*)&buf[item * 4] = v;   // xs[i][px][c]
    }
    __syncthreads();

    // ---- metric conv: 7 params x 16 patches, 3 independent chains (per channel)
    if (t < 112) {
        int prm = t >> 4, g = t & 15;
        const float* wrow = &mws[prm * KK];
        float acc0 = 0.0f, acc1 = 0.0f, acc2 = 0.0f;
        #pragma unroll 1
        for (int i = 0; i < 7; ++i) {
            const float* bp = &buf[(i * NPX + g * 7) * 4];
            const float* w0 = &wrow[i * 7];
            const float* w1 = &wrow[49 + i * 7];
            const float* w2 = &wrow[98 + i * 7];
            #pragma unroll
            for (int j = 0; j < 7; ++j) {
                acc0 = fmaf(bp[j * 4 + 0], w0[j], acc0);
                acc1 = fmaf(bp[j * 4 + 1], w1[j], acc1);
                acc2 = fmaf(bp[j * 4 + 2], w2[j], acc2);
            }
        }
        par_s[g][prm] = mb[prm] + acc0 + acc1 + acc2;
    }
    __syncthreads();

    // ---- derived quantities (proven math)
    if (t < GG) {
        float a0 = par_s[t][0], a1 = par_s[t][1], a2 = par_s[t][2], a3 = par_s[t][3];
        float a4 = par_s[t][4], a5 = par_s[t][5], a6 = par_s[t][6];
        float nrm = sqrtf(a0 * a0 + a1 * a1);
        float inv = 1.0f / fmaxf(nrm, 1e-12f);
        float v0 = a0 * inv, v1 = a1 * inv;
        float e0 = 2.0f * sigmoidf_(a2);
        float e1 = 2.0f * sigmoidf_(a3);
        float sc = 0.5f + 1.5f * sigmoidf_(a4);
        e0 *= sc; e1 *= sc;
        float wn  = sqrtf(a5 * a5 + a6 * a6);
        float wsc = 0.5f * sigmoidf_(wn);
        der_s[t][0] = e0 * v0 * v0 + e1 * v1 * v1;
        der_s[t][1] = (e0 - e1) * v0 * v1;
        der_s[t][2] = e0 * v1 * v1 + e1 * v0 * v0;
        der_s[t][3] = a5 * wsc;
        der_s[t][4] = a6 * wsc;
    }
    __syncthreads();

    // ---- gather, PAIR-BATCHED: both items' geometry first, then all 8
    // global_load_dwordx4 issued back-to-back, then both interps. Doubles
    // in-flight scattered loads vs the compiler's serialized schedule (r2/r3
    // lesson: this phase is serialized-load-latency-bound, not BW-bound).
    // 784 items = 3*256 + 16: pairs {t, t+256}, {t+512, t+768(t<16 only)}.
    #pragma unroll
    for (int half = 0; half < 2; ++half) {
        int itemA = half * 512 + t;
        int itemB = itemA + 256;
        bool validB = (itemB < GG * NDIR);
        int itemBc = validB ? itemB : 0;

        int gA, nA, a00, a01, a10, a11;  float cA00, cA01, cA10, cA11;
        int gB, nB, b00, b01, b10, b11;  float cB00, cB01, cB10, cB11;
        geom_(itemA,  row0, col0, dirs, der_s, gA, nA, a00, a01, a10, a11, cA00, cA01, cA10, cA11);
        geom_(itemBc, row0, col0, dirs, der_s, gB, nB, b00, b01, b10, b11, cB00, cB01, cB10, cB11);

        f32x4 qa0 = *(const f32x4*)(xp + (pbase + (size_t)a00) * 4);
        f32x4 qa1 = *(const f32x4*)(xp + (pbase + (size_t)a01) * 4);
        f32x4 qa2 = *(const f32x4*)(xp + (pbase + (size_t)a10) * 4);
        f32x4 qa3 = *(const f32x4*)(xp + (pbase + (size_t)a11) * 4);
        f32x4 qb0 = *(const f32x4*)(xp + (pbase + (size_t)b00) * 4);
        f32x4 qb1 = *(const f32x4*)(xp + (pbase + (size_t)b01) * 4);
        f32x4 qb2 = *(const f32x4*)(xp + (pbase + (size_t)b10) * 4);
        f32x4 qb3 = *(const f32x4*)(xp + (pbase + (size_t)b11) * 4);

        #pragma unroll
        for (int c = 0; c < CIN; ++c) {
            buf[(c * NDIR + nA) * SSTR + gA] =
                qa0[c] * cA00 + qa1[c] * cA01 + qa2[c] * cA10 + qa3[c] * cA11;
        }
        if (validB) {
            #pragma unroll
            for (int c = 0; c < CIN; ++c) {
                buf[(c * NDIR + nB) * SSTR + gB] =
                    qb0[c] * cB00 + qb1[c] * cB01 + qb2[c] * cB10 + qb3[c] * cB11;
            }
        }
    }
    __syncthreads();

    // ---- MFMA projection GEMM, operand-swapped (r3, verified): A = pw rows
    // (M=e), B = samp (N=m). Each lane owns 4 consecutive e of one output row
    // -> 6x global_store_dwordx4 per thread, vectorized bias add.
    const int lane = t & 63;
    const int wv   = t >> 6;           // 0..3; wave handles 6 E-tiles
    const int nrow = lane & 15;        // m within block
    const int hi   = lane >> 4;        // k-chunk / e-subrow

    bf16x8 sfr[5];
    #pragma unroll
    for (int ks = 0; ks < 5; ++ks) {
        #pragma unroll
        for (int j = 0; j < 8; ++j) {
            int k = ks * 32 + hi * 8 + j;
            float v = (k < KK) ? buf[k * SSTR + nrow] : 0.0f;
            sfr[ks][j] = (__bf16)v;
        }
    }

    float* orow = out + (m0 + nrow) * EE;
    #pragma unroll
    for (int q = 0; q < 6; ++q) {
        int tile = wv * 6 + q;
        int erow = tile * 16 + nrow;
        const unsigned short* arow = pwB + (size_t)erow * KPAD + hi * 8;
        f32x4 acc = {0.0f, 0.0f, 0.0f, 0.0f};
        #pragma unroll
        for (int ks = 0; ks < 5; ++ks) {
            bf16x8 afr = *(const bf16x8*)&arow[ks * 32];
            acc = __builtin_amdgcn_mfma_f32_16x16x32_bf16(afr, sfr[ks], acc, 0, 0, 0);
        }
        int e0 = tile * 16 + hi * 4;
        f32x4 b4 = *(const f32x4*)&pb[e0];
        f32x4 o = acc + b4;
        *(f32x4*)&orow[e0] = o;
    }
}

// planar fallback (no packed workspace): round-0-style gather
__launch_bounds__(TB, 6)
__global__ void fused_planar_kernel(const float* __restrict__ x,
                                    const float* __restrict__ mw,
                                    const float* __restrict__ mb,
                                    const unsigned short* __restrict__ pwB,
                                    const float* __restrict__ pb,
                                    float* __restrict__ out) {
    __shared__ float mws[7 * KK];
    __shared__ float dirs[NDIR][3];
    __shared__ float par_s[GG][8];
    __shared__ float der_s[GG][5];
    __shared__ __align__(16) float buf[2512];

    const int t   = threadIdx.x;
    const int blk = blockIdx.x;
    const int b   = blk >> 6;
    const int rem = blk & 63;
    const int hp  = rem >> 1;
    const int wp0 = (rem & 1) * GG;
    const size_t m0 = (size_t)blk * GG;
    const int row0 = hp * PP;
    const int col0 = wp0 * PP;
    const float* xb = x + (size_t)b * (CIN * HH * WW);

    for (int i = t; i < 7 * KK; i += TB) mws[i] = mw[i];
    if (t >= 64 && t < 64 + NDIR) {
        int n = t - 64;
        float u0, u1, s;
        if (n == 0)      { u0 = 1.0f; u1 = 0.0f; s = 0.0f; }
        else if (n < 9)  { float th = (float)(n - 1)  * 0.78539816339744831f; u0 = cosf(th); u1 = sinf(th); s = 0.33333334f; }
        else if (n < 25) { float th = (float)(n - 9)  * 0.39269908169872414f; u0 = cosf(th); u1 = sinf(th); s = 0.66666669f; }
        else             { float th = (float)(n - 25) * 0.26179938779914941f; u0 = cosf(th); u1 = sinf(th); s = 1.0f; }
        dirs[n][0] = u0; dirs[n][1] = u1; dirs[n][2] = s;
    }
    for (int item = t; item < CIN * 7 * NPX; item += TB) {
        int c = item / (7 * NPX), r2 = item - c * (7 * NPX);
        int i = r2 / NPX, px = r2 - i * NPX;
        buf[item] = xb[(size_t)c * (HH * WW) + (size_t)(row0 + i) * WW + col0 + px];
    }
    __syncthreads();
    if (t < 112) {
        int prm = t >> 4, g = t & 15;
        const float* wrow = &mws[prm * KK];
        float acc0 = 0.0f, acc1 = 0.0f, acc2 = 0.0f;
        #pragma unroll 1
        for (int i = 0; i < 7; ++i) {
            const float* b0 = &buf[(0 * 7 + i) * NPX + g * 7];
            const float* b1 = &buf[(1 * 7 + i) * NPX + g * 7];
            const float* b2 = &buf[(2 * 7 + i) * NPX + g * 7];
            #pragma unroll
            for (int j = 0; j < 7; ++j) {
                acc0 = fmaf(b0[j], wrow[i * 7 + j], acc0);
                acc1 = fmaf(b1[j], wrow[49 + i * 7 + j], acc1);
                acc2 = fmaf(b2[j], wrow[98 + i * 7 + j], acc2);
            }
        }
        par_s[g][prm] = mb[prm] + acc0 + acc1 + acc2;
    }
    __syncthreads();
    if (t < GG) {
        float a0 = par_s[t][0], a1 = par_s[t][1], a2 = par_s[t][2], a3 = par_s[t][3];
        float a4 = par_s[t][4], a5 = par_s[t][5], a6 = par_s[t][6];
        float nrm = sqrtf(a0 * a0 + a1 * a1);
        float inv = 1.0f / fmaxf(nrm, 1e-12f);
        float v0 = a0 * inv, v1 = a1 * inv;
        float e0 = 2.0f * sigmoidf_(a2);
        float e1 = 2.0f * sigmoidf_(a3);
        float sc = 0.5f + 1.5f * sigmoidf_(a4);
        e0 *= sc; e1 *= sc;
        float wn  = sqrtf(a5 * a5 + a6 * a6);
        float wsc = 0.5f * sigmoidf_(wn);
        der_s[t][0] = e0 * v0 * v0 + e1 * v1 * v1;
        der_s[t][1] = (e0 - e1) * v0 * v1;
        der_s[t][2] = e0 * v1 * v1 + e1 * v0 * v0;
        der_s[t][3] = a5 * wsc;
        der_s[t][4] = a6 * wsc;
    }
    __syncthreads();
    for (int item = t; item < GG * NDIR; item += TB) {
        int g, n, o00, o01, o10, o11; float c00, c01, c10, c11;
        geom_(item, row0, col0, dirs, der_s, g, n, o00, o01, o10, o11, c00, c01, c10, c11);
        #pragma unroll
        for (int c = 0; c < CIN; ++c) {
            const float* xc = xb + c * (HH * WW);
            buf[(c * NDIR + n) * SSTR + g] =
                xc[o00] * c00 + xc[o01] * c01 + xc[o10] * c10 + xc[o11] * c11;
        }
    }
    __syncthreads();
    const int lane = t & 63;
    const int wv   = t >> 6;
    const int nrow = lane & 15;
    const int hi   = lane >> 4;
    bf16x8 sfr[5];
    #pragma unroll
    for (int ks = 0; ks < 5; ++ks) {
        #pragma unroll
        for (int j = 0; j < 8; ++j) {
            int k = ks * 32 + hi * 8 + j;
            float v = (k < KK) ? buf[k * SSTR + nrow] : 0.0f;
            sfr[ks][j] = (__bf16)v;
        }
    }
    float* orow = out + (m0 + nrow) * EE;
    #pragma unroll
    for (int q = 0; q < 6; ++q) {
        int tile = wv * 6 + q;
        int erow = tile * 16 + nrow;
        const unsigned short* arow = pwB + (size_t)erow * KPAD + hi * 8;
        f32x4 acc = {0.0f, 0.0f, 0.0f, 0.0f};
        #pragma unroll
        for (int ks = 0; ks < 5; ++ks) {
            bf16x8 afr = *(const bf16x8*)&arow[ks * 32];
            acc = __builtin_amdgcn_mfma_f32_16x16x32_bf16(afr, sfr[ks], acc, 0, 0, 0);
        }
        int e0 = tile * 16 + hi * 4;
        f32x4 b4 = *(const f32x4*)&pb[e0];
        f32x4 o = acc + b4;
        *(f32x4*)&orow[e0] = o;
    }
}

extern "C" void kernel_launch(void* const* d_in, const int* in_sizes, int n_in,
                              void* d_out, int out_size, void* d_ws, size_t ws_size,
                              hipStream_t stream) {
    const float* x  = (const float*)d_in[0];
    const float* mw = (const float*)d_in[1];
    const float* mb = (const float*)d_in[2];
    const float* pw = (const float*)d_in[3];
    const float* pb = (const float*)d_in[4];
    float* out = (float*)d_out;

    unsigned short* pwB = (unsigned short*)d_ws;                       // 120 KB (128 KB slot)
    float* xp = (float*)((char*)d_ws + (size_t)(1 << 17));             // packed NHW4 image

    const int B = in_sizes[0] / (CIN * HH * WW);   // 64
    const int npix = B * HH * WW;
    const int npix4 = npix / 4;
    const size_t need = (size_t)(1 << 17) + (size_t)npix * 4 * sizeof(float);
    const bool packed = ws_size >= need;

    if (packed) {
        int grid = (npix4 > EE * KPAD ? npix4 : EE * KPAD);
        pack_kernel<<<(grid + 255) / 256, 256, 0, stream>>>(x, pw, xp, pwB, npix4);
        fused_kernel<<<B * 64, TB, 0, stream>>>(x, xp, mw, mb, pwB, pb, out);
    } else {
        pack_kernel<<<(EE * KPAD + 255) / 256, 256, 0, stream>>>(x, pw, xp, pwB, 0);
        fused_planar_kernel<<<B * 64, TB, 0, stream>>>(x, mw, mb, pwB, pb, out);
    }
}

// Round 6
// 204.180 us; speedup vs baseline: 1.0523x; 1.0095x over previous
//
#include <hip/hip_runtime.h>
#include <math.h>

#define PP   7
#define NDIR 49
#define CIN  3
#define KK   147      // CIN * 49
#define KPAD 160      // bf16 weight row stride: 5 k-steps of 32, zero-padded tail
#define EE   384
#define HH   224
#define WW   224
#define GG   16       // patches per block
#define TB   256
#define NPX  112      // GG*PP pixel columns per block strip
#define WSTR 208      // packed metric-weight row stride (floats), 16B-aligned rows
#define SROW 164      // samp row stride (floats): 147 data + zero pad, 16B-aligned rows
#define SSTR 17       // legacy samp stride (planar fallback kernel only)

typedef __attribute__((ext_vector_type(8))) __bf16 bf16x8;
typedef __attribute__((ext_vector_type(4))) float  f32x4;

__device__ __forceinline__ float sigmoidf_(float v) {
    return 1.0f / (1.0f + expf(-v));
}

// ---- K0: fused pack.
// (a) proj_w (E,K) fp32 -> bf16 [E][KPAD];
// (b) x NCHW -> NHW4 fp32 (channel-interleaved float4, 4th lane zero) — worth
//     ~43 us in the fused gather (r3 A/B) for ~16 us of streaming cost;
// (c) metric_w -> mwg[prm][(i*7+j)*4 + c] (pixel-iteration order, 16B rows):
//     lets the fused conv read pixels AND weights as ds_read_b128.
__global__ void pack_kernel(const float* __restrict__ x,
                            const float* __restrict__ pw,
                            const float* __restrict__ mw,
                            float* __restrict__ xp,
                            unsigned short* __restrict__ pwB,
                            float* __restrict__ mwg,
                            int npix4) {
    int idx = blockIdx.x * blockDim.x + threadIdx.x;
    if (idx < EE * KPAD) {
        int e = idx / KPAD;
        int k = idx - e * KPAD;
        float v = (k < KK) ? pw[e * KK + k] : 0.0f;
        __bf16 h = (__bf16)v;
        pwB[idx] = *(unsigned short*)&h;
    }
    if (idx < 7 * WSTR) {
        int prm = idx / WSTR, r = idx - prm * WSTR;
        float v = 0.0f;
        if (r < 196) {
            int q = r >> 2, c = r & 3;        // q = i*7+j in 0..48
            if (c < 3) v = mw[prm * KK + c * 49 + q];
        }
        mwg[idx] = v;
    }
    if (idx < npix4) {
        const int ppi = HH * WW / 4;         // 12544 pixel-quads per image
        int b = idx / ppi;
        int p = (idx - b * ppi) * 4;
        const float* xb = x + (size_t)b * (CIN * HH * WW) + p;
        f32x4 r0 = *(const f32x4*)(xb);
        f32x4 r1 = *(const f32x4*)(xb + HH * WW);
        f32x4 r2 = *(const f32x4*)(xb + 2 * HH * WW);
        float* op = xp + ((size_t)b * (HH * WW) + p) * 4;
        #pragma unroll
        for (int i = 0; i < 4; ++i) {
            f32x4 v = {r0[i], r1[i], r2[i], 0.0f};
            *(f32x4*)(op + i * 4) = v;
        }
    }
}

// ---- K1: fused metric-conv + derived params + packed gather + MFMA GEMM.
// r2's proven structure + LDS-layout fixes:
//  * conv: 2x ds_read_b128 + 3 FMA per (i,j) (was 6x ds_read_b32) — the conv
//    phase was ~590 wave-instrs of LDS-pipe occupancy per block, the largest
//    single LDS consumer.
//  * samp transposed to [g][k] (stride 164, zero-padded tail): GEMM A-fragment
//    = 2x ds_read_b128 per ks (was 8x ds_read_b32), no k<KK guard.
// (256,8): r2 A/B showed 8 blocks/CU beats the ILP-friendlier (256,6).
__launch_bounds__(TB, 8)
__global__ void fused_kernel(const float* __restrict__ xp,   // packed NHW4
                             const float* __restrict__ mwg,  // packed metric w
                             const float* __restrict__ mb,
                             const unsigned short* __restrict__ pwB,
                             const float* __restrict__ pb,
                             float* __restrict__ out) {
    __shared__ __align__(16) float mwp_s[7 * WSTR];  // 5824 B
    __shared__ float dirs[NDIR][3];                  //  588 B
    __shared__ float par_s[GG][8];                   //  512 B
    __shared__ float der_s[GG][5];                   //  320 B
    // union: phase A = strip [7][112][4] = 3136 fl; phase B = samp[16][164] = 2624 fl
    __shared__ __align__(16) float buf[3136];        // 12544 B; total ~19.5 KB

    const int t   = threadIdx.x;
    const int blk = blockIdx.x;
    const int b   = blk >> 6;
    const int rem = blk & 63;
    const int hp  = rem >> 1;
    const int wp0 = (rem & 1) * GG;
    const size_t m0 = (size_t)blk * GG;
    const int row0 = hp * PP;
    const int col0 = wp0 * PP;

    // ---- init: packed metric weights (coalesced b128) + direction table
    for (int i4 = t; i4 < 7 * WSTR / 4; i4 += TB)
        *(f32x4*)&mwp_s[i4 * 4] = *(const f32x4*)&mwg[i4 * 4];
    if (t >= 64 && t < 64 + NDIR) {
        int n = t - 64;
        float u0, u1, s;
        if (n == 0)      { u0 = 1.0f; u1 = 0.0f; s = 0.0f; }
        else if (n < 9)  { float th = (float)(n - 1)  * 0.78539816339744831f; u0 = cosf(th); u1 = sinf(th); s = 0.33333334f; }
        else if (n < 25) { float th = (float)(n - 9)  * 0.39269908169872414f; u0 = cosf(th); u1 = sinf(th); s = 0.66666669f; }
        else             { float th = (float)(n - 25) * 0.26179938779914941f; u0 = cosf(th); u1 = sinf(th); s = 1.0f; }
        dirs[n][0] = u0; dirs[n][1] = u1; dirs[n][2] = s;
    }

    // ---- stage the block's 7x112 strip into LDS (coalesced dwordx4)
    const size_t pbase = (size_t)b * (HH * WW);
    for (int item = t; item < 7 * NPX; item += TB) {
        int i = item / NPX, px = item - i * NPX;
        f32x4 v = *(const f32x4*)(xp + (pbase + (size_t)(row0 + i) * WW + col0 + px) * 4);
        *(f32x4*)&buf[item * 4] = v;   // xs[i][px][c]
    }
    __syncthreads();

    // ---- metric conv: 7 params x 16 patches. Per (i,j): one b128 pixel quad
    // + one b128 weight quad + 3 chained FMAs (per-channel accumulators).
    if (t < 112) {
        int prm = t >> 4, g = t & 15;
        const float* wrow = &mwp_s[prm * WSTR];
        float acc0 = 0.0f, acc1 = 0.0f, acc2 = 0.0f;
        #pragma unroll 1
        for (int i = 0; i < 7; ++i) {
            const float* bp = &buf[(i * NPX + g * 7) * 4];
            const float* wp = &wrow[i * 28];
            #pragma unroll
            for (int j = 0; j < 7; ++j) {
                f32x4 pix = *(const f32x4*)&bp[j * 4];
                f32x4 w4  = *(const f32x4*)&wp[j * 4];
                acc0 = fmaf(pix[0], w4[0], acc0);
                acc1 = fmaf(pix[1], w4[1], acc1);
                acc2 = fmaf(pix[2], w4[2], acc2);
            }
        }
        par_s[g][prm] = mb[prm] + acc0 + acc1 + acc2;
    }
    __syncthreads();

    // ---- derived quantities (t<16) + samp tail zero-fill (others).
    // Strip is dead past the conv barrier; gather writes only k<147, so the
    // k=147..163 pad is filled here, race-free.
    if (t < GG) {
        float a0 = par_s[t][0], a1 = par_s[t][1], a2 = par_s[t][2], a3 = par_s[t][3];
        float a4 = par_s[t][4], a5 = par_s[t][5], a6 = par_s[t][6];
        float nrm = sqrtf(a0 * a0 + a1 * a1);
        float inv = 1.0f / fmaxf(nrm, 1e-12f);
        float v0 = a0 * inv, v1 = a1 * inv;
        float e0 = 2.0f * sigmoidf_(a2);
        float e1 = 2.0f * sigmoidf_(a3);
        float sc = 0.5f + 1.5f * sigmoidf_(a4);
        e0 *= sc; e1 *= sc;
        float wn  = sqrtf(a5 * a5 + a6 * a6);
        float wsc = 0.5f * sigmoidf_(wn);
        der_s[t][0] = e0 * v0 * v0 + e1 * v1 * v1;
        der_s[t][1] = (e0 - e1) * v0 * v1;
        der_s[t][2] = e0 * v1 * v1 + e1 * v0 * v0;
        der_s[t][3] = a5 * wsc;
        der_s[t][4] = a6 * wsc;
    }
    for (int z = t; z < GG * (SROW - KK); z += TB) {
        int g = z / (SROW - KK), r = z - g * (SROW - KK);
        buf[g * SROW + KK + r] = 0.0f;
    }
    __syncthreads();

    // ---- positions + bilinear gather into samp[g][k] (r2's proven simple loop;
    // r4 lesson: hand-batched load scheduling loses to this).
    for (int item = t; item < GG * NDIR; item += TB) {
        int g = item / NDIR;
        int n = item - g * NDIR;
        float u0 = dirs[n][0], u1 = dirs[n][1], s = dirs[n][2];
        float M00 = der_s[g][0], M01 = der_s[g][1], M11 = der_s[g][2];
        float w0 = der_s[g][3], w1 = der_s[g][4];
        float quad  = u0 * u0 * M00 + 2.0f * u0 * u1 * M01 + u1 * u1 * M11;
        float drift = w0 * u0 + w1 * u1;
        float F = sqrtf(quad + 1e-6f) + drift;
        float r = s / (F + 1e-6f);
        float py = (float)(row0 + 3) + u1 * r;
        float px = (float)(col0 + g * PP + 3) + u0 * r;
        float y0f = floorf(py), x0f = floorf(px);
        float y1f = y0f + 1.0f, x1f = x0f + 1.0f;
        float wy = py - y0f, wx = px - x0f;
        float c00 = (1.0f - wy) * (1.0f - wx);
        float c01 = (1.0f - wy) * wx;
        float c10 = wy * (1.0f - wx);
        float c11 = wy * wx;
        bool vy0 = (y0f >= 0.0f) && (y0f <= (float)(HH - 1));
        bool vy1 = (y1f >= 0.0f) && (y1f <= (float)(HH - 1));
        bool vx0 = (x0f >= 0.0f) && (x0f <= (float)(WW - 1));
        bool vx1 = (x1f >= 0.0f) && (x1f <= (float)(WW - 1));
        c00 *= (vy0 && vx0) ? 1.0f : 0.0f;
        c01 *= (vy0 && vx1) ? 1.0f : 0.0f;
        c10 *= (vy1 && vx0) ? 1.0f : 0.0f;
        c11 *= (vy1 && vx1) ? 1.0f : 0.0f;
        int iy0 = (int)fminf(fmaxf(y0f, 0.0f), (float)(HH - 1));
        int iy1 = (int)fminf(fmaxf(y1f, 0.0f), (float)(HH - 1));
        int ix0 = (int)fminf(fmaxf(x0f, 0.0f), (float)(WW - 1));
        int ix1 = (int)fminf(fmaxf(x1f, 0.0f), (float)(WW - 1));
        f32x4 q00 = *(const f32x4*)(xp + (pbase + (size_t)(iy0 * WW + ix0)) * 4);
        f32x4 q01 = *(const f32x4*)(xp + (pbase + (size_t)(iy0 * WW + ix1)) * 4);
        f32x4 q10 = *(const f32x4*)(xp + (pbase + (size_t)(iy1 * WW + ix0)) * 4);
        f32x4 q11 = *(const f32x4*)(xp + (pbase + (size_t)(iy1 * WW + ix1)) * 4);
        #pragma unroll
        for (int c = 0; c < CIN; ++c) {
            buf[g * SROW + c * NDIR + n] =
                q00[c] * c00 + q01[c] * c01 + q10[c] * c10 + q11[c] * c11;
        }
    }
    __syncthreads();

    // ---- MFMA projection GEMM, operand-swapped (r3/r4 verified): A = pw rows
    // (M=e), B = samp (N=m). A-fragment from samp row nrow: 2x ds_read_b128/ks.
    const int lane = t & 63;
    const int wv   = t >> 6;           // 0..3; wave handles 6 E-tiles
    const int nrow = lane & 15;        // m within block
    const int hi   = lane >> 4;        // k-chunk / e-subrow

    bf16x8 sfr[5];
    const float* srow = &buf[nrow * SROW];
    #pragma unroll
    for (int ks = 0; ks < 5; ++ks) {
        f32x4 lo = *(const f32x4*)&srow[ks * 32 + hi * 8];
        f32x4 hv = *(const f32x4*)&srow[ks * 32 + hi * 8 + 4];
        #pragma unroll
        for (int j = 0; j < 4; ++j) sfr[ks][j] = (__bf16)lo[j];
        #pragma unroll
        for (int j = 0; j < 4; ++j) sfr[ks][4 + j] = (__bf16)hv[j];
    }

    float* orow = out + (m0 + nrow) * EE;
    #pragma unroll
    for (int q = 0; q < 6; ++q) {
        int tile = wv * 6 + q;
        int erow = tile * 16 + nrow;
        const unsigned short* arow = pwB + (size_t)erow * KPAD + hi * 8;
        f32x4 acc = {0.0f, 0.0f, 0.0f, 0.0f};
        #pragma unroll
        for (int ks = 0; ks < 5; ++ks) {
            bf16x8 afr = *(const bf16x8*)&arow[ks * 32];
            acc = __builtin_amdgcn_mfma_f32_16x16x32_bf16(afr, sfr[ks], acc, 0, 0, 0);
        }
        int e0 = tile * 16 + hi * 4;
        f32x4 b4 = *(const f32x4*)&pb[e0];
        f32x4 o = acc + b4;
        *(f32x4*)&orow[e0] = o;
    }
}

// ---- planar fallback (only if workspace can't hold the packed image)
__launch_bounds__(TB, 6)
__global__ void fused_planar_kernel(const float* __restrict__ x,
                                    const float* __restrict__ mw,
                                    const float* __restrict__ mb,
                                    const unsigned short* __restrict__ pwB,
                                    const float* __restrict__ pb,
                                    float* __restrict__ out) {
    __shared__ float mws[7 * KK];
    __shared__ float dirs[NDIR][3];
    __shared__ float par_s[GG][8];
    __shared__ float der_s[GG][5];
    __shared__ __align__(16) float buf[2512];

    const int t   = threadIdx.x;
    const int blk = blockIdx.x;
    const int b   = blk >> 6;
    const int rem = blk & 63;
    const int hp  = rem >> 1;
    const int wp0 = (rem & 1) * GG;
    const size_t m0 = (size_t)blk * GG;
    const int row0 = hp * PP;
    const int col0 = wp0 * PP;
    const float* xb = x + (size_t)b * (CIN * HH * WW);

    for (int i = t; i < 7 * KK; i += TB) mws[i] = mw[i];
    if (t >= 64 && t < 64 + NDIR) {
        int n = t - 64;
        float u0, u1, s;
        if (n == 0)      { u0 = 1.0f; u1 = 0.0f; s = 0.0f; }
        else if (n < 9)  { float th = (float)(n - 1)  * 0.78539816339744831f; u0 = cosf(th); u1 = sinf(th); s = 0.33333334f; }
        else if (n < 25) { float th = (float)(n - 9)  * 0.39269908169872414f; u0 = cosf(th); u1 = sinf(th); s = 0.66666669f; }
        else             { float th = (float)(n - 25) * 0.26179938779914941f; u0 = cosf(th); u1 = sinf(th); s = 1.0f; }
        dirs[n][0] = u0; dirs[n][1] = u1; dirs[n][2] = s;
    }
    for (int item = t; item < CIN * 7 * NPX; item += TB) {
        int c = item / (7 * NPX), r2 = item - c * (7 * NPX);
        int i = r2 / NPX, px = r2 - i * NPX;
        buf[item] = xb[(size_t)c * (HH * WW) + (size_t)(row0 + i) * WW + col0 + px];
    }
    __syncthreads();
    if (t < 112) {
        int prm = t >> 4, g = t & 15;
        const float* wrow = &mws[prm * KK];
        float acc0 = 0.0f, acc1 = 0.0f, acc2 = 0.0f;
        #pragma unroll 1
        for (int i = 0; i < 7; ++i) {
            const float* b0 = &buf[(0 * 7 + i) * NPX + g * 7];
            const float* b1 = &buf[(1 * 7 + i) * NPX + g * 7];
            const float* b2 = &buf[(2 * 7 + i) * NPX + g * 7];
            #pragma unroll
            for (int j = 0; j < 7; ++j) {
                acc0 = fmaf(b0[j], wrow[i * 7 + j], acc0);
                acc1 = fmaf(b1[j], wrow[49 + i * 7 + j], acc1);
                acc2 = fmaf(b2[j], wrow[98 + i * 7 + j], acc2);
            }
        }
        par_s[g][prm] = mb[prm] + acc0 + acc1 + acc2;
    }
    __syncthreads();
    if (t < GG) {
        float a0 = par_s[t][0], a1 = par_s[t][1], a2 = par_s[t][2], a3 = par_s[t][3];
        float a4 = par_s[t][4], a5 = par_s[t][5], a6 = par_s[t][6];
        float nrm = sqrtf(a0 * a0 + a1 * a1);
        float inv = 1.0f / fmaxf(nrm, 1e-12f);
        float v0 = a0 * inv, v1 = a1 * inv;
        float e0 = 2.0f * sigmoidf_(a2);
        float e1 = 2.0f * sigmoidf_(a3);
        float sc = 0.5f + 1.5f * sigmoidf_(a4);
        e0 *= sc; e1 *= sc;
        float wn  = sqrtf(a5 * a5 + a6 * a6);
        float wsc = 0.5f * sigmoidf_(wn);
        der_s[t][0] = e0 * v0 * v0 + e1 * v1 * v1;
        der_s[t][1] = (e0 - e1) * v0 * v1;
        der_s[t][2] = e0 * v1 * v1 + e1 * v0 * v0;
        der_s[t][3] = a5 * wsc;
        der_s[t][4] = a6 * wsc;
    }
    __syncthreads();
    for (int item = t; item < GG * NDIR; item += TB) {
        int g = item / NDIR;
        int n = item - g * NDIR;
        float u0 = dirs[n][0], u1 = dirs[n][1], s = dirs[n][2];
        float M00 = der_s[g][0], M01 = der_s[g][1], M11 = der_s[g][2];
        float w0 = der_s[g][3], w1 = der_s[g][4];
        float quad  = u0 * u0 * M00 + 2.0f * u0 * u1 * M01 + u1 * u1 * M11;
        float drift = w0 * u0 + w1 * u1;
        float F = sqrtf(quad + 1e-6f) + drift;
        float r = s / (F + 1e-6f);
        float py = (float)(row0 + 3) + u1 * r;
        float px = (float)(col0 + g * PP + 3) + u0 * r;
        float y0f = floorf(py), x0f = floorf(px);
        float y1f = y0f + 1.0f, x1f = x0f + 1.0f;
        float wy = py - y0f, wx = px - x0f;
        float c00 = (1.0f - wy) * (1.0f - wx);
        float c01 = (1.0f - wy) * wx;
        float c10 = wy * (1.0f - wx);
        float c11 = wy * wx;
        bool vy0 = (y0f >= 0.0f) && (y0f <= (float)(HH - 1));
        bool vy1 = (y1f >= 0.0f) && (y1f <= (float)(HH - 1));
        bool vx0 = (x0f >= 0.0f) && (x0f <= (float)(WW - 1));
        bool vx1 = (x1f >= 0.0f) && (x1f <= (float)(WW - 1));
        c00 *= (vy0 && vx0) ? 1.0f : 0.0f;
        c01 *= (vy0 && vx1) ? 1.0f : 0.0f;
        c10 *= (vy1 && vx0) ? 1.0f : 0.0f;
        c11 *= (vy1 && vx1) ? 1.0f : 0.0f;
        int iy0 = (int)fminf(fmaxf(y0f, 0.0f), (float)(HH - 1));
        int iy1 = (int)fminf(fmaxf(y1f, 0.0f), (float)(HH - 1));
        int ix0 = (int)fminf(fmaxf(x0f, 0.0f), (float)(WW - 1));
        int ix1 = (int)fminf(fmaxf(x1f, 0.0f), (float)(WW - 1));
        int o00 = iy0 * WW + ix0, o01 = iy0 * WW + ix1;
        int o10 = iy1 * WW + ix0, o11 = iy1 * WW + ix1;
        #pragma unroll
        for (int c = 0; c < CIN; ++c) {
            const float* xc = xb + c * (HH * WW);
            buf[(c * NDIR + n) * SSTR + g] =
                xc[o00] * c00 + xc[o01] * c01 + xc[o10] * c10 + xc[o11] * c11;
        }
    }
    __syncthreads();
    const int lane = t & 63;
    const int wv   = t >> 6;
    const int nrow = lane & 15;
    const int hi   = lane >> 4;
    bf16x8 sfr[5];
    #pragma unroll
    for (int ks = 0; ks < 5; ++ks) {
        #pragma unroll
        for (int j = 0; j < 8; ++j) {
            int k = ks * 32 + hi * 8 + j;
            float v = (k < KK) ? buf[k * SSTR + nrow] : 0.0f;
            sfr[ks][j] = (__bf16)v;
        }
    }
    float* orow = out + (m0 + nrow) * EE;
    #pragma unroll
    for (int q = 0; q < 6; ++q) {
        int tile = wv * 6 + q;
        int erow = tile * 16 + nrow;
        const unsigned short* arow = pwB + (size_t)erow * KPAD + hi * 8;
        f32x4 acc = {0.0f, 0.0f, 0.0f, 0.0f};
        #pragma unroll
        for (int ks = 0; ks < 5; ++ks) {
            bf16x8 afr = *(const bf16x8*)&arow[ks * 32];
            acc = __builtin_amdgcn_mfma_f32_16x16x32_bf16(afr, sfr[ks], acc, 0, 0, 0);
        }
        int e0 = tile * 16 + hi * 4;
        f32x4 b4 = *(const f32x4*)&pb[e0];
        f32x4 o = acc + b4;
        *(f32x4*)&orow[e0] = o;
    }
}

extern "C" void kernel_launch(void* const* d_in, const int* in_sizes, int n_in,
                              void* d_out, int out_size, void* d_ws, size_t ws_size,
                              hipStream_t stream) {
    const float* x  = (const float*)d_in[0];
    const float* mw = (const float*)d_in[1];
    const float* mb = (const float*)d_in[2];
    const float* pw = (const float*)d_in[3];
    const float* pb = (const float*)d_in[4];
    float* out = (float*)d_out;

    // workspace: [0,120K) pwB | [120K,~126K) mwg | [128K, ...) packed image
    unsigned short* pwB = (unsigned short*)d_ws;                       // 122880 B
    float* mwg = (float*)((char*)d_ws + (size_t)(EE * KPAD) * 2);      // 5824 B (fits slot)
    float* xp  = (float*)((char*)d_ws + (size_t)(1 << 17));

    const int B = in_sizes[0] / (CIN * HH * WW);   // 64
    const int npix = B * HH * WW;
    const int npix4 = npix / 4;
    const size_t need = (size_t)(1 << 17) + (size_t)npix * 4 * sizeof(float);
    const bool packed = ws_size >= need;

    if (packed) {
        int grid = (npix4 > EE * KPAD ? npix4 : EE * KPAD);
        pack_kernel<<<(grid + 255) / 256, 256, 0, stream>>>(x, pw, mw, xp, pwB, mwg, npix4);
        fused_kernel<<<B * 64, TB, 0, stream>>>(xp, mwg, mb, pwB, pb, out);
    } else {
        pack_kernel<<<(EE * KPAD + 255) / 256, 256, 0, stream>>>(x, pw, mw, xp, pwB, mwg, 0);
        fused_planar_kernel<<<B * 64, TB, 0, stream>>>(x, mw, mb, pwB, pb, out);
    }
}